// Round 9
// baseline (238.128 us; speedup 1.0000x reference)
//
#include <hip/hip_runtime.h>
#include <hip/hip_bf16.h>
#include <stdint.h>

typedef __attribute__((ext_vector_type(8))) short short8;
typedef __attribute__((ext_vector_type(4))) float f32x4;
typedef unsigned short ushort_t;

#define MFMA16(a, b, c) __builtin_amdgcn_mfma_f32_16x16x32_bf16((a), (b), (c), 0, 0, 0)
#define EXP2F(x) __builtin_amdgcn_exp2f(x)
#define BAR() __builtin_amdgcn_s_barrier()

// B=8 S=1024 D=1024 H=16 hd=64; M = B*S = 8192; N = 3*D = 3072; K = 1024

__device__ __forceinline__ float bf2f(unsigned short u) {
    union { unsigned int i; float f; } x; x.i = ((unsigned int)u) << 16; return x.f;
}
__device__ __forceinline__ unsigned short f2bf(float f) {
    union { float f; unsigned int i; } x; x.f = f;
    unsigned int i = x.i;
    i = i + 0x7FFFu + ((i >> 16) & 1u);   // RNE
    return (unsigned short)(i >> 16);
}
__device__ __forceinline__ unsigned int pack2(float a, float b) {
    return (unsigned int)f2bf(a) | ((unsigned int)f2bf(b) << 16);
}
__device__ __forceinline__ void glds16(const void* gsrc, void* ldst) {
    __builtin_amdgcn_global_load_lds(
        (const __attribute__((address_space(1))) unsigned int*)gsrc,
        (__attribute__((address_space(3))) unsigned int*)ldst, 16, 0, 0);
}

// ---------------- kernel 1: fused prep v2 — per-instruction coalesced (frozen) ---------
__global__ __launch_bounds__(256) void prep_kernel(
    const float* __restrict__ hidden,   // (8192,1024)
    const float* __restrict__ W,        // (3072,1024)
    const float* __restrict__ loraA,    // (5,4,1024)
    const int* __restrict__ adapter_mask,
    ushort_t* __restrict__ Hb,
    ushort_t* __restrict__ Wb,
    float4* __restrict__ lo)
{
    int tid = threadIdx.x;
    int wave = tid >> 6, lane = tid & 63;
    int row = blockIdx.x * 4 + wave;     // 0..11263
    if (row < 8192) {
        int b = row >> 10;
        int a = adapter_mask[b];
        const float4* hp = (const float4*)(hidden + (size_t)row * 1024);
        float4 hv[4];
#pragma unroll
        for (int c = 0; c < 4; ++c) hv[c] = hp[c * 64 + lane];
#pragma unroll
        for (int c = 0; c < 4; ++c) {
            uint2 pk;
            pk.x = pack2(hv[c].x, hv[c].y);
            pk.y = pack2(hv[c].z, hv[c].w);
            *(uint2*)(Hb + (size_t)row * 1024 + c * 256 + lane * 4) = pk;
        }
        const float4* Ap = (const float4*)(loraA + (size_t)a * 4096);
        float acc[4];
#pragma unroll
        for (int r = 0; r < 4; ++r) {
            float s = 0.f;
#pragma unroll
            for (int c = 0; c < 4; ++c) {
                float4 av = Ap[(size_t)r * 256 + c * 64 + lane];
                s += hv[c].x * av.x + hv[c].y * av.y + hv[c].z * av.z + hv[c].w * av.w;
            }
            acc[r] = s;
        }
        for (int off = 32; off > 0; off >>= 1)
#pragma unroll
            for (int r = 0; r < 4; ++r) acc[r] += __shfl_xor(acc[r], off);
        if (lane == 0) lo[row] = make_float4(acc[0], acc[1], acc[2], acc[3]);
    } else {
        int rw = row - 8192;             // 0..3071
        const float4* wp = (const float4*)(W + (size_t)rw * 1024);
        float4 wv[4];
#pragma unroll
        for (int c = 0; c < 4; ++c) wv[c] = wp[c * 64 + lane];
#pragma unroll
        for (int c = 0; c < 4; ++c) {
            uint2 pk;
            pk.x = pack2(wv[c].x, wv[c].y);
            pk.y = pack2(wv[c].z, wv[c].w);
            *(uint2*)(Wb + (size_t)rw * 1024 + c * 256 + lane * 4) = pk;
        }
    }
}

// ---------------- kernel 2: qkv GEMM v6 — m97-exact structure + XOR swizzle ----------
// BM=BN=128, BK=32, 256 thr (4 waves 2x2, wave tile 64x64), LDS 32KB dbuf ->
// 5 blocks/CU (m114 cross-block overlap hides the per-tile vmcnt(0) drain —
// the mechanism the 1-block/CU 256^2 variants could not have). Grid 24x64=1536
// at 5/CU ~ 1.2 rounds. Per K-tile: stage(t+1) FIRST (4x glds16, overlaps
// reads+MFMA), 8x ds_read_b128, 16 MFMA, one __syncthreads (vmcnt0+lgkm0+bar).
// Chunk swizzle c ^ ((row>>1)&3) on both stage source and frag read: 16-lane
// groups cover all 32 banks (2-way = free, m136) — kills round-0's 6.3M conflicts.
__global__ __launch_bounds__(256, 4) void qkv_gemm_kernel(
    const ushort_t* __restrict__ Hb,   // (8192,1024) bf16
    const ushort_t* __restrict__ Wb,   // (3072,1024) bf16
    const float* __restrict__ bias,    // (3072)
    const float4* __restrict__ lo,     // (8192)
    const float* __restrict__ loraB,   // (5,3072,4)
    const int* __restrict__ adapter_mask, // (8)
    const float* __restrict__ cosp,    // (8,1024,64)
    const float* __restrict__ sinp,
    ushort_t* __restrict__ qw,
    ushort_t* __restrict__ kw,
    ushort_t* __restrict__ vt)
{
    __shared__ __align__(16) ushort_t As[2][4096];   // 2 x 8KB
    __shared__ __align__(16) ushort_t Bs[2][4096];   // 2 x 8KB
    int tid = threadIdx.x;
    int wave = tid >> 6, lane = tid & 63, quad = lane >> 4, l16 = lane & 15;
    int mq = (wave >> 1) * 64, nq = (wave & 1) * 64;

    // bijective XCD swizzle: 1536 blocks = 8 * 192
    int wg = (blockIdx.x & 7) * 192 + (blockIdx.x >> 3);
    int bx = wg % 24, by = wg / 24;
    int n0 = bx * 128;
    int m0 = by * 128;

    // staging: thread -> row r_=tid>>2 (64 rows/unit), phys slot tid&3,
    // source chunk c_ = slot ^ ((row>>1)&3)  (XOR involution)
    int r_ = tid >> 2;
    int c_ = (tid & 3) ^ ((tid >> 3) & 3);
    const ushort_t* pA0 = Hb + (size_t)(m0 + r_) * 1024 + c_ * 8;
    const ushort_t* pA1 = pA0 + (size_t)64 * 1024;
    const ushort_t* pB0 = Wb + (size_t)(n0 + r_) * 1024 + c_ * 8;
    const ushort_t* pB1 = pB0 + (size_t)64 * 1024;
    char* dA = (char*)&As[0][0] + wave * 1024;   // + buf*8192 + unit*4096
    char* dB = (char*)&Bs[0][0] + wave * 1024;

    // fragment read byte offsets (row*64 + swizzled chunk*16)
    int offA[4], offB[4];
#pragma unroll
    for (int i = 0; i < 4; ++i) {
        int ra = mq + i * 16 + l16;
        offA[i] = ra * 64 + ((quad ^ ((ra >> 1) & 3)) * 16);
        int rb = nq + i * 16 + l16;
        offB[i] = rb * 64 + ((quad ^ ((rb >> 1) & 3)) * 16);
    }

    f32x4 acc[4][4];
#pragma unroll
    for (int i = 0; i < 4; ++i)
#pragma unroll
        for (int j = 0; j < 4; ++j) acc[i][j] = (f32x4)0.f;

    // prologue: stage tile 0 into buf 0
    glds16(pA0, dA);  glds16(pA1, dA + 4096);
    glds16(pB0, dB);  glds16(pB1, dB + 4096);
    __syncthreads();

#pragma unroll 2
    for (int t = 0; t < 32; ++t) {
        int cur = t & 1;
        // stage t+1 first: DMA overlaps this tile's reads + MFMA
        if (t < 31) {
            int k = (t + 1) * 32;
            char* sA = dA + (cur ^ 1) * 8192;
            char* sB = dB + (cur ^ 1) * 8192;
            glds16(pA0 + k, sA);  glds16(pA1 + k, sA + 4096);
            glds16(pB0 + k, sB);  glds16(pB1 + k, sB + 4096);
        }
        const char* rA = (const char*)&As[0][0] + cur * 8192;
        const char* rB = (const char*)&Bs[0][0] + cur * 8192;
        short8 af[4], bf[4];
#pragma unroll
        for (int i = 0; i < 4; ++i) af[i] = *(const short8*)(rA + offA[i]);
#pragma unroll
        for (int i = 0; i < 4; ++i) bf[i] = *(const short8*)(rB + offB[i]);
#pragma unroll
        for (int mi = 0; mi < 4; ++mi)
#pragma unroll
            for (int ni = 0; ni < 4; ++ni)
                acc[mi][ni] = MFMA16(af[mi], bf[ni], acc[mi][ni]);
        __syncthreads();   // vmcnt(0)+lgkmcnt(0)+barrier: tile t+1 staged, reads done
    }

    // epilogue: bias + lora + rope + scatter (round-0 verified code)
    int t_qkv = n0 >> 10;        // 0=q 1=k 2=v, block-uniform (128 | 1024)
    int b = m0 >> 10;            // block-uniform
    int a_idx = adapter_mask[b];
    float bi[4], bb[4][4];
    int cpos[4], chh[4];
#pragma unroll
    for (int ni = 0; ni < 4; ++ni) {
        int c = n0 + nq + ni * 16 + l16;
        bi[ni] = bias[c];
        const float* Bp = loraB + ((size_t)a_idx * 3072 + c) * 4;
        bb[ni][0] = Bp[0]; bb[ni][1] = Bp[1]; bb[ni][2] = Bp[2]; bb[ni][3] = Bp[3];
        cpos[ni] = c & 63; chh[ni] = (c >> 6) & 15;
    }
#pragma unroll
    for (int mi = 0; mi < 4; ++mi) {
        float vals[4][4];   // [r][ni]
#pragma unroll
        for (int r = 0; r < 4; ++r) {
            int m = m0 + mq + mi * 16 + quad * 4 + r;
            float4 lov = lo[m];
#pragma unroll
            for (int ni = 0; ni < 4; ++ni)
                vals[r][ni] = acc[mi][ni][r] + bi[ni]
                      + 0.25f * (lov.x * bb[ni][0] + lov.y * bb[ni][1]
                               + lov.z * bb[ni][2] + lov.w * bb[ni][3]);
        }
        int s0 = (m0 + mq + mi * 16 + quad * 4) & 1023;
        if (t_qkv < 2) {
#pragma unroll
            for (int r = 0; r < 4; ++r) {
                int s = s0 + r;
                size_t cb = ((size_t)b * 1024 + s) * 64;
                float cA = cosp[cb + l16],      sA_ = sinp[cb + l16];
                float cB = cosp[cb + 16 + l16], sB_ = sinp[cb + 16 + l16];
                float w0 = vals[r][0] * cA - vals[r][2] * sA_;
                float w2 = vals[r][2] * cA + vals[r][0] * sA_;
                float w1 = vals[r][1] * cB - vals[r][3] * sB_;
                float w3 = vals[r][3] * cB + vals[r][1] * sB_;
                float v[4] = {w0, w1, w2, w3};
#pragma unroll
                for (int ni = 0; ni < 4; ++ni) {
                    size_t bh = (size_t)b * 16 + chh[ni];
                    ushort_t ob = f2bf(v[ni]);
                    if (t_qkv == 0) qw[(bh * 1024 + s) * 64 + cpos[ni]] = ob;
                    else            kw[(bh * 1024 + s) * 64 + cpos[ni]] = ob;
                }
            }
        } else {
#pragma unroll
            for (int ni = 0; ni < 4; ++ni) {
                uint2 pk;
                pk.x = pack2(vals[0][ni], vals[1][ni]);
                pk.y = pack2(vals[2][ni], vals[3][ni]);
                size_t bh = (size_t)b * 16 + chh[ni];
                *(uint2*)&vt[(bh * 64 + cpos[ni]) * 1024 + s0] = pk;
            }
        }
    }
}

// ---------------- kernel 3: attention v3 — 2 q-tiles per block (round-8, frozen) -------
__global__ __launch_bounds__(256, 2) void attn_kernel(
    const ushort_t* __restrict__ qw,   // (B,H,S,hd) bf16 (rope applied)
    const ushort_t* __restrict__ kw,   // (B,H,S,hd) bf16 (rope applied)
    const ushort_t* __restrict__ vt,   // (B,H,hd,S) bf16
    const float* __restrict__ mask,    // (B,1,1,S) f32
    float* __restrict__ out)           // (B,S,H*hd) f32
{
    __shared__ __align__(16) ushort_t Kt[3][4096];    // 24KB
    __shared__ __align__(16) ushort_t Vt[3][4096];    // 24KB
    __shared__ __align__(16) ushort_t Ps[4][32][72];  // 18KB (per-wave)
    __shared__ float mlds[1024];                      // 4KB  (total 70KB -> 2 blk/CU)
    const float KSCALE = 0.125f * 1.44269504f;
    int tid = threadIdx.x;
    int wave = tid >> 6, lane = tid & 63, quad = lane >> 4, l16 = lane & 15;
    int id = blockIdx.x;
    int qp = id >> 7;             // 0..3 (256 q-rows each)
    int bh = id & 127;            // 0..127 (id%8 == bh%8 -> XCD-local K/V)
    int b = bh >> 4, h = bh & 15;
    size_t base = (size_t)bh * 65536;
    int q0 = qp * 256 + wave * 32;          // phase 0 rows; phase 1: +128

    for (int i = tid; i < 1024; i += 256) mlds[i] = mask[b * 1024 + i] * 1.44269504f;

    const ushort_t* kbase = kw + base;
    const ushort_t* vbase = vt + base;

    int n0 = tid, n1 = tid + 256;
    int r0 = n0 >> 3, c0 = (n0 & 7) ^ (r0 & 7);
    int r1 = n1 >> 3, c1 = (n1 & 7) ^ (r1 & 7);

    short8 qf[4][2];
    for (int mt = 0; mt < 4; ++mt) {
        int qr = q0 + (mt >> 1) * 128 + (mt & 1) * 16;
        for (int kt = 0; kt < 2; ++kt)
            qf[mt][kt] = *(const short8*)(qw + base + (size_t)(qr + l16) * 64 + kt * 32 + quad * 8);
    }

    f32x4 oacc[4][4], sum_acc[4];
    for (int mt = 0; mt < 4; ++mt) {
        sum_acc[mt] = (f32x4)0.f;
        for (int nt = 0; nt < 4; ++nt) oacc[mt][nt] = (f32x4)0.f;
    }

    short8 ones;
    for (int j = 0; j < 8; ++j) ones[j] = (short)0x3F80;   // bf16 1.0

    __syncthreads();   // mlds visible (one-time; no staging outstanding yet)

    int koff[4][2], voff[4][2];
    for (int nt = 0; nt < 4; ++nt)
        for (int kt = 0; kt < 2; ++kt) {
            int rr = nt * 16 + l16;
            int cc = (kt * 4 + quad) ^ (rr & 7);
            koff[nt][kt] = (rr * 8 + cc) * 8;
            voff[nt][kt] = (rr * 8 + cc) * 8;
        }

    {
        char* kd = (char*)&Kt[0][0] + wave * 1024;
        char* vd = (char*)&Vt[0][0] + wave * 1024;
        glds16(kbase + (size_t)r0 * 64 + c0 * 8, kd);
        glds16(kbase + (size_t)r1 * 64 + c1 * 8, kd + 4096);
        glds16(vbase + (size_t)r0 * 1024 + c0 * 8, vd);
        glds16(vbase + (size_t)r1 * 1024 + c1 * 8, vd + 4096);
        kd = (char*)&Kt[1][0] + wave * 1024;
        vd = (char*)&Vt[1][0] + wave * 1024;
        glds16(kbase + (size_t)(64 + r0) * 64 + c0 * 8, kd);
        glds16(kbase + (size_t)(64 + r1) * 64 + c1 * 8, kd + 4096);
        glds16(vbase + (size_t)r0 * 1024 + 64 + c0 * 8, vd);
        glds16(vbase + (size_t)r1 * 1024 + 64 + c1 * 8, vd + 4096);
    }

    const ushort_t* kR  = &Kt[0][0];  const ushort_t* vR  = &Vt[0][0];
    const ushort_t* kN1 = &Kt[1][0];  const ushort_t* vN1 = &Vt[1][0];
    const ushort_t* kN2 = &Kt[2][0];  const ushort_t* vN2 = &Vt[2][0];

    for (int it = 0; it < 16; ++it) {
        int kt0 = it * 64;
        if (it < 15) { asm volatile("s_waitcnt vmcnt(4)" ::: "memory"); }
        else         { asm volatile("s_waitcnt vmcnt(0)" ::: "memory"); }
        BAR();
        __builtin_amdgcn_sched_barrier(0);
        if (it < 14) {
            int kn = kt0 + 128;
            char* kd = (char*)kN2 + wave * 1024;
            char* vd = (char*)vN2 + wave * 1024;
            glds16(kbase + (size_t)(kn + r0) * 64 + c0 * 8, kd);
            glds16(kbase + (size_t)(kn + r1) * 64 + c1 * 8, kd + 4096);
            glds16(vbase + (size_t)r0 * 1024 + kn + c0 * 8, vd);
            glds16(vbase + (size_t)r1 * 1024 + kn + c1 * 8, vd + 4096);
        }
        float mv[4];
        for (int nt = 0; nt < 4; ++nt) mv[nt] = mlds[kt0 + nt * 16 + l16];

#pragma unroll
        for (int ph = 0; ph < 2; ++ph) {
            f32x4 sacc[2][4];
            {
                short8 kf[4][2];
#pragma unroll
                for (int nt = 0; nt < 4; ++nt)
#pragma unroll
                    for (int kt = 0; kt < 2; ++kt)
                        kf[nt][kt] = *(const short8*)&kR[koff[nt][kt]];
#pragma unroll
                for (int mt = 0; mt < 2; ++mt)
#pragma unroll
                    for (int nt = 0; nt < 4; ++nt) {
                        f32x4 z = (f32x4)0.f;
                        z = MFMA16(qf[ph * 2 + mt][0], kf[nt][0], z);
                        z = MFMA16(qf[ph * 2 + mt][1], kf[nt][1], z);
                        sacc[mt][nt] = z;
                    }
            }
#pragma unroll
            for (int mt = 0; mt < 2; ++mt)
#pragma unroll
                for (int nt = 0; nt < 4; ++nt)
#pragma unroll
                    for (int r = 0; r < 4; ++r) {
                        float p = EXP2F(sacc[mt][nt][r] * KSCALE + mv[nt]);
                        Ps[wave][mt * 16 + quad * 4 + r][nt * 16 + l16] = f2bf(p);
                    }
            short8 pf[2][2];
#pragma unroll
            for (int mt = 0; mt < 2; ++mt)
#pragma unroll
                for (int kt = 0; kt < 2; ++kt)
                    pf[mt][kt] = *(const short8*)&Ps[wave][mt * 16 + l16][kt * 32 + quad * 8];
            {
                short8 vf[4][2];
#pragma unroll
                for (int nt = 0; nt < 4; ++nt)
#pragma unroll
                    for (int kt = 0; kt < 2; ++kt)
                        vf[nt][kt] = *(const short8*)&vR[voff[nt][kt]];
#pragma unroll
                for (int mt = 0; mt < 2; ++mt) {
#pragma unroll
                    for (int nt = 0; nt < 4; ++nt) {
                        oacc[ph * 2 + mt][nt] = MFMA16(pf[mt][0], vf[nt][0], oacc[ph * 2 + mt][nt]);
                        oacc[ph * 2 + mt][nt] = MFMA16(pf[mt][1], vf[nt][1], oacc[ph * 2 + mt][nt]);
                    }
                    sum_acc[ph * 2 + mt] = MFMA16(pf[mt][0], ones, sum_acc[ph * 2 + mt]);
                    sum_acc[ph * 2 + mt] = MFMA16(pf[mt][1], ones, sum_acc[ph * 2 + mt]);
                }
            }
        }
        const ushort_t* tk = kR; kR = kN1; kN1 = kN2; kN2 = tk;
        const ushort_t* tv = vR; vR = vN1; vN1 = vN2; vN2 = tv;
    }

    for (int mt = 0; mt < 4; ++mt) {
        for (int r = 0; r < 4; ++r) {
            float inv = 1.f / sum_acc[mt][r];
            int s = q0 + (mt >> 1) * 128 + (mt & 1) * 16 + quad * 4 + r;
            size_t ob = ((size_t)b * 1024 + s) * 1024 + h * 64;
            for (int nt = 0; nt < 4; ++nt)
                out[ob + nt * 16 + l16] = oacc[mt][nt][r] * inv;
        }
    }
}

extern "C" void kernel_launch(void* const* d_in, const int* in_sizes, int n_in,
                              void* d_out, int out_size, void* d_ws, size_t ws_size,
                              hipStream_t stream)
{
    const float* hidden = (const float*)d_in[0];
    const float* mask   = (const float*)d_in[1];
    const float* cosp   = (const float*)d_in[2];
    const float* sinp   = (const float*)d_in[3];
    const int* adapter_mask = (const int*)d_in[4];
    const float* W      = (const float*)d_in[5];
    const float* bias   = (const float*)d_in[6];
    const float* loraA  = (const float*)d_in[7];
    const float* loraB  = (const float*)d_in[8];
    float* out = (float*)d_out;

    char* ws = (char*)d_ws;
    float4* lo = (float4*)ws;                                  // 128 KB
    ushort_t* qw = (ushort_t*)(ws + (1 << 20));                // 16 MB each
    ushort_t* kw = qw + (size_t)8 * 16 * 1024 * 64;
    ushort_t* vt = kw + (size_t)8 * 16 * 1024 * 64;            // total 49 MB (proven fits)

    ushort_t* Hb = (ushort_t*)d_out;                           // 16 MB
    ushort_t* Wb = Hb + (size_t)8192 * 1024;                   // 6 MB

    prep_kernel<<<2816, 256, 0, stream>>>(hidden, W, loraA, adapter_mask, Hb, Wb, lo);
    qkv_gemm_kernel<<<1536, 256, 0, stream>>>(Hb, Wb, bias, lo, loraB, adapter_mask,
                                              cosp, sinp, qw, kw, vt);
    attn_kernel<<<512, 256, 0, stream>>>(qw, kw, vt, mask, out);
}

// Round 10
// 228.255 us; speedup vs baseline: 1.0433x; 1.0433x over previous
//
#include <hip/hip_runtime.h>
#include <hip/hip_bf16.h>
#include <stdint.h>

typedef __attribute__((ext_vector_type(8))) short short8;
typedef __attribute__((ext_vector_type(4))) float f32x4;
typedef unsigned short ushort_t;

#define MFMA16(a, b, c) __builtin_amdgcn_mfma_f32_16x16x32_bf16((a), (b), (c), 0, 0, 0)
#define EXP2F(x) __builtin_amdgcn_exp2f(x)
#define BAR() __builtin_amdgcn_s_barrier()
#define CFENCE() asm volatile("" ::: "memory")

// B=8 S=1024 D=1024 H=16 hd=64; M = B*S = 8192; N = 3*D = 3072; K = 1024

__device__ __forceinline__ float bf2f(unsigned short u) {
    union { unsigned int i; float f; } x; x.i = ((unsigned int)u) << 16; return x.f;
}
__device__ __forceinline__ unsigned short f2bf(float f) {
    union { float f; unsigned int i; } x; x.f = f;
    unsigned int i = x.i;
    i = i + 0x7FFFu + ((i >> 16) & 1u);   // RNE
    return (unsigned short)(i >> 16);
}
__device__ __forceinline__ unsigned int pack2(float a, float b) {
    return (unsigned int)f2bf(a) | ((unsigned int)f2bf(b) << 16);
}
__device__ __forceinline__ void glds16(const void* gsrc, void* ldst) {
    __builtin_amdgcn_global_load_lds(
        (const __attribute__((address_space(1))) unsigned int*)gsrc,
        (__attribute__((address_space(3))) unsigned int*)ldst, 16, 0, 0);
}

// ---------------- kernel 1: fused prep v2 — per-instruction coalesced (frozen) ---------
__global__ __launch_bounds__(256) void prep_kernel(
    const float* __restrict__ hidden,   // (8192,1024)
    const float* __restrict__ W,        // (3072,1024)
    const float* __restrict__ loraA,    // (5,4,1024)
    const int* __restrict__ adapter_mask,
    ushort_t* __restrict__ Hb,
    ushort_t* __restrict__ Wb,
    float4* __restrict__ lo)
{
    int tid = threadIdx.x;
    int wave = tid >> 6, lane = tid & 63;
    int row = blockIdx.x * 4 + wave;     // 0..11263
    if (row < 8192) {
        int b = row >> 10;
        int a = adapter_mask[b];
        const float4* hp = (const float4*)(hidden + (size_t)row * 1024);
        float4 hv[4];
#pragma unroll
        for (int c = 0; c < 4; ++c) hv[c] = hp[c * 64 + lane];
#pragma unroll
        for (int c = 0; c < 4; ++c) {
            uint2 pk;
            pk.x = pack2(hv[c].x, hv[c].y);
            pk.y = pack2(hv[c].z, hv[c].w);
            *(uint2*)(Hb + (size_t)row * 1024 + c * 256 + lane * 4) = pk;
        }
        const float4* Ap = (const float4*)(loraA + (size_t)a * 4096);
        float acc[4];
#pragma unroll
        for (int r = 0; r < 4; ++r) {
            float s = 0.f;
#pragma unroll
            for (int c = 0; c < 4; ++c) {
                float4 av = Ap[(size_t)r * 256 + c * 64 + lane];
                s += hv[c].x * av.x + hv[c].y * av.y + hv[c].z * av.z + hv[c].w * av.w;
            }
            acc[r] = s;
        }
        for (int off = 32; off > 0; off >>= 1)
#pragma unroll
            for (int r = 0; r < 4; ++r) acc[r] += __shfl_xor(acc[r], off);
        if (lane == 0) lo[row] = make_float4(acc[0], acc[1], acc[2], acc[3]);
    } else {
        int rw = row - 8192;             // 0..3071
        const float4* wp = (const float4*)(W + (size_t)rw * 1024);
        float4 wv[4];
#pragma unroll
        for (int c = 0; c < 4; ++c) wv[c] = wp[c * 64 + lane];
#pragma unroll
        for (int c = 0; c < 4; ++c) {
            uint2 pk;
            pk.x = pack2(wv[c].x, wv[c].y);
            pk.y = pack2(wv[c].z, wv[c].w);
            *(uint2*)(Wb + (size_t)rw * 1024 + c * 256 + lane * 4) = pk;
        }
    }
}

// ---------------- kernel 2: qkv GEMM v7 — 128^2/BK=32, TRIPLE-buffered counted pipeline --
// r9 geometry + attn-r3's proven pipeline: 3 bufs (48KB -> 3 blocks/CU), prefetch
// distance 2, per K-tile ONE {vmcnt(4); s_barrier} (never a full drain in-loop),
// stage(t+2) issued AFTER the barrier.
// Ledger: prologue stages tile0->buf0, tile1->buf1 (8 loads). Entry of iter t:
// outstanding = stage(t)[4 oldest] + stage(t+1)[4] -> vmcnt(4) drains own stage(t);
// barrier makes ALL waves' stage(t) LDS-visible (each drained its own pre-barrier).
// WAR: stage(t+2)->buf[(t+2)%3] whose last readers (iter t-1) finished before this
// barrier in program order. CFENCE after BAR stops compiler hoisting glds16
// (s_barrier intrinsic is IntrNoMem). Rotation via named pointers (rule #20).
__global__ __launch_bounds__(256, 3) void qkv_gemm_kernel(
    const ushort_t* __restrict__ Hb,   // (8192,1024) bf16
    const ushort_t* __restrict__ Wb,   // (3072,1024) bf16
    const float* __restrict__ bias,    // (3072)
    const float4* __restrict__ lo,     // (8192)
    const float* __restrict__ loraB,   // (5,3072,4)
    const int* __restrict__ adapter_mask, // (8)
    const float* __restrict__ cosp,    // (8,1024,64)
    const float* __restrict__ sinp,
    ushort_t* __restrict__ qw,
    ushort_t* __restrict__ kw,
    ushort_t* __restrict__ vt)
{
    __shared__ __align__(16) ushort_t As[3][4096];   // 3 x 8KB = 24KB
    __shared__ __align__(16) ushort_t Bs[3][4096];   // 24KB  (total 48KB -> 3 blk/CU)
    int tid = threadIdx.x;
    int wave = tid >> 6, lane = tid & 63, quad = lane >> 4, l16 = lane & 15;
    int mq = (wave >> 1) * 64, nq = (wave & 1) * 64;

    // bijective XCD swizzle: 1536 blocks = 8 * 192
    int wg = (blockIdx.x & 7) * 192 + (blockIdx.x >> 3);
    int bx = wg % 24, by = wg / 24;
    int n0 = bx * 128;
    int m0 = by * 128;

    // staging: thread -> row r_=tid>>2 (64 rows/unit), phys slot tid&3,
    // source chunk c_ = slot ^ ((row>>1)&3)  (XOR involution)
    int r_ = tid >> 2;
    int c_ = (tid & 3) ^ ((tid >> 3) & 3);
    const ushort_t* pA0 = Hb + (size_t)(m0 + r_) * 1024 + c_ * 8;
    const ushort_t* pA1 = pA0 + (size_t)64 * 1024;
    const ushort_t* pB0 = Wb + (size_t)(n0 + r_) * 1024 + c_ * 8;
    const ushort_t* pB1 = pB0 + (size_t)64 * 1024;
    int woff = wave * 1024;

    // fragment read byte offsets (row*64 + swizzled chunk*16)
    int offA[4], offB[4];
#pragma unroll
    for (int i = 0; i < 4; ++i) {
        int ra = mq + i * 16 + l16;
        offA[i] = ra * 64 + ((quad ^ ((ra >> 1) & 3)) * 16);
        int rb = nq + i * 16 + l16;
        offB[i] = rb * 64 + ((quad ^ ((rb >> 1) & 3)) * 16);
    }

    f32x4 acc[4][4];
#pragma unroll
    for (int i = 0; i < 4; ++i)
#pragma unroll
        for (int j = 0; j < 4; ++j) acc[i][j] = (f32x4)0.f;

    // rotating buffer base pointers (tile t, t+1, t+2)
    char* bA_r  = (char*)&As[0][0];  char* bB_r  = (char*)&Bs[0][0];
    char* bA_n1 = (char*)&As[1][0];  char* bB_n1 = (char*)&Bs[1][0];
    char* bA_n2 = (char*)&As[2][0];  char* bB_n2 = (char*)&Bs[2][0];

    // prologue: stage tile0 -> buf0, tile1 -> buf1 (FIFO oldest-first: tile0's 4 first)
    glds16(pA0,      bA_r  + woff);  glds16(pA1,      bA_r  + woff + 4096);
    glds16(pB0,      bB_r  + woff);  glds16(pB1,      bB_r  + woff + 4096);
    glds16(pA0 + 32, bA_n1 + woff);  glds16(pA1 + 32, bA_n1 + woff + 4096);
    glds16(pB0 + 32, bB_n1 + woff);  glds16(pB1 + 32, bB_n1 + woff + 4096);

    for (int t = 0; t < 32; ++t) {
        // entry: drain own stage(t) (oldest 4), keep stage(t+1) in flight
        if (t < 31) { asm volatile("s_waitcnt vmcnt(4)" ::: "memory"); }
        else        { asm volatile("s_waitcnt vmcnt(0)" ::: "memory"); }
        BAR();
        CFENCE();
        if (t < 30) {
            int k = (t + 2) * 32;
            glds16(pA0 + k, bA_n2 + woff);  glds16(pA1 + k, bA_n2 + woff + 4096);
            glds16(pB0 + k, bB_n2 + woff);  glds16(pB1 + k, bB_n2 + woff + 4096);
        }
        short8 af[4], bf[4];
#pragma unroll
        for (int i = 0; i < 4; ++i) af[i] = *(const short8*)(bA_r + offA[i]);
#pragma unroll
        for (int i = 0; i < 4; ++i) bf[i] = *(const short8*)(bB_r + offB[i]);
#pragma unroll
        for (int mi = 0; mi < 4; ++mi)
#pragma unroll
            for (int ni = 0; ni < 4; ++ni)
                acc[mi][ni] = MFMA16(af[mi], bf[ni], acc[mi][ni]);
        // rotate: r <- n1 <- n2 <- r
        char* tA = bA_r; bA_r = bA_n1; bA_n1 = bA_n2; bA_n2 = tA;
        char* tB = bB_r; bB_r = bB_n1; bB_n1 = bB_n2; bB_n2 = tB;
    }

    // epilogue: bias + lora + rope + scatter (round-9 verified code)
    int t_qkv = n0 >> 10;        // 0=q 1=k 2=v, block-uniform (128 | 1024)
    int b = m0 >> 10;            // block-uniform
    int a_idx = adapter_mask[b];
    float bi[4], bb[4][4];
    int cpos[4], chh[4];
#pragma unroll
    for (int ni = 0; ni < 4; ++ni) {
        int c = n0 + nq + ni * 16 + l16;
        bi[ni] = bias[c];
        const float* Bp = loraB + ((size_t)a_idx * 3072 + c) * 4;
        bb[ni][0] = Bp[0]; bb[ni][1] = Bp[1]; bb[ni][2] = Bp[2]; bb[ni][3] = Bp[3];
        cpos[ni] = c & 63; chh[ni] = (c >> 6) & 15;
    }
#pragma unroll
    for (int mi = 0; mi < 4; ++mi) {
        float vals[4][4];   // [r][ni]
#pragma unroll
        for (int r = 0; r < 4; ++r) {
            int m = m0 + mq + mi * 16 + quad * 4 + r;
            float4 lov = lo[m];
#pragma unroll
            for (int ni = 0; ni < 4; ++ni)
                vals[r][ni] = acc[mi][ni][r] + bi[ni]
                      + 0.25f * (lov.x * bb[ni][0] + lov.y * bb[ni][1]
                               + lov.z * bb[ni][2] + lov.w * bb[ni][3]);
        }
        int s0 = (m0 + mq + mi * 16 + quad * 4) & 1023;
        if (t_qkv < 2) {
#pragma unroll
            for (int r = 0; r < 4; ++r) {
                int s = s0 + r;
                size_t cb = ((size_t)b * 1024 + s) * 64;
                float cA = cosp[cb + l16],      sA_ = sinp[cb + l16];
                float cB = cosp[cb + 16 + l16], sB_ = sinp[cb + 16 + l16];
                float w0 = vals[r][0] * cA - vals[r][2] * sA_;
                float w2 = vals[r][2] * cA + vals[r][0] * sA_;
                float w1 = vals[r][1] * cB - vals[r][3] * sB_;
                float w3 = vals[r][3] * cB + vals[r][1] * sB_;
                float v[4] = {w0, w1, w2, w3};
#pragma unroll
                for (int ni = 0; ni < 4; ++ni) {
                    size_t bh = (size_t)b * 16 + chh[ni];
                    ushort_t ob = f2bf(v[ni]);
                    if (t_qkv == 0) qw[(bh * 1024 + s) * 64 + cpos[ni]] = ob;
                    else            kw[(bh * 1024 + s) * 64 + cpos[ni]] = ob;
                }
            }
        } else {
#pragma unroll
            for (int ni = 0; ni < 4; ++ni) {
                uint2 pk;
                pk.x = pack2(vals[0][ni], vals[1][ni]);
                pk.y = pack2(vals[2][ni], vals[3][ni]);
                size_t bh = (size_t)b * 16 + chh[ni];
                *(uint2*)&vt[(bh * 64 + cpos[ni]) * 1024 + s0] = pk;
            }
        }
    }
}

// ---------------- kernel 3: attention v3 — 2 q-tiles per block (round-8, frozen) -------
__global__ __launch_bounds__(256, 2) void attn_kernel(
    const ushort_t* __restrict__ qw,   // (B,H,S,hd) bf16 (rope applied)
    const ushort_t* __restrict__ kw,   // (B,H,S,hd) bf16 (rope applied)
    const ushort_t* __restrict__ vt,   // (B,H,hd,S) bf16
    const float* __restrict__ mask,    // (B,1,1,S) f32
    float* __restrict__ out)           // (B,S,H*hd) f32
{
    __shared__ __align__(16) ushort_t Kt[3][4096];    // 24KB
    __shared__ __align__(16) ushort_t Vt[3][4096];    // 24KB
    __shared__ __align__(16) ushort_t Ps[4][32][72];  // 18KB (per-wave)
    __shared__ float mlds[1024];                      // 4KB  (total 70KB -> 2 blk/CU)
    const float KSCALE = 0.125f * 1.44269504f;
    int tid = threadIdx.x;
    int wave = tid >> 6, lane = tid & 63, quad = lane >> 4, l16 = lane & 15;
    int id = blockIdx.x;
    int qp = id >> 7;             // 0..3 (256 q-rows each)
    int bh = id & 127;            // 0..127 (id%8 == bh%8 -> XCD-local K/V)
    int b = bh >> 4, h = bh & 15;
    size_t base = (size_t)bh * 65536;
    int q0 = qp * 256 + wave * 32;          // phase 0 rows; phase 1: +128

    for (int i = tid; i < 1024; i += 256) mlds[i] = mask[b * 1024 + i] * 1.44269504f;

    const ushort_t* kbase = kw + base;
    const ushort_t* vbase = vt + base;

    int n0 = tid, n1 = tid + 256;
    int r0 = n0 >> 3, c0 = (n0 & 7) ^ (r0 & 7);
    int r1 = n1 >> 3, c1 = (n1 & 7) ^ (r1 & 7);

    short8 qf[4][2];
    for (int mt = 0; mt < 4; ++mt) {
        int qr = q0 + (mt >> 1) * 128 + (mt & 1) * 16;
        for (int kt = 0; kt < 2; ++kt)
            qf[mt][kt] = *(const short8*)(qw + base + (size_t)(qr + l16) * 64 + kt * 32 + quad * 8);
    }

    f32x4 oacc[4][4], sum_acc[4];
    for (int mt = 0; mt < 4; ++mt) {
        sum_acc[mt] = (f32x4)0.f;
        for (int nt = 0; nt < 4; ++nt) oacc[mt][nt] = (f32x4)0.f;
    }

    short8 ones;
    for (int j = 0; j < 8; ++j) ones[j] = (short)0x3F80;   // bf16 1.0

    __syncthreads();   // mlds visible (one-time; no staging outstanding yet)

    int koff[4][2], voff[4][2];
    for (int nt = 0; nt < 4; ++nt)
        for (int kt = 0; kt < 2; ++kt) {
            int rr = nt * 16 + l16;
            int cc = (kt * 4 + quad) ^ (rr & 7);
            koff[nt][kt] = (rr * 8 + cc) * 8;
            voff[nt][kt] = (rr * 8 + cc) * 8;
        }

    {
        char* kd = (char*)&Kt[0][0] + wave * 1024;
        char* vd = (char*)&Vt[0][0] + wave * 1024;
        glds16(kbase + (size_t)r0 * 64 + c0 * 8, kd);
        glds16(kbase + (size_t)r1 * 64 + c1 * 8, kd + 4096);
        glds16(vbase + (size_t)r0 * 1024 + c0 * 8, vd);
        glds16(vbase + (size_t)r1 * 1024 + c1 * 8, vd + 4096);
        kd = (char*)&Kt[1][0] + wave * 1024;
        vd = (char*)&Vt[1][0] + wave * 1024;
        glds16(kbase + (size_t)(64 + r0) * 64 + c0 * 8, kd);
        glds16(kbase + (size_t)(64 + r1) * 64 + c1 * 8, kd + 4096);
        glds16(vbase + (size_t)r0 * 1024 + 64 + c0 * 8, vd);
        glds16(vbase + (size_t)r1 * 1024 + 64 + c1 * 8, vd + 4096);
    }

    const ushort_t* kR  = &Kt[0][0];  const ushort_t* vR  = &Vt[0][0];
    const ushort_t* kN1 = &Kt[1][0];  const ushort_t* vN1 = &Vt[1][0];
    const ushort_t* kN2 = &Kt[2][0];  const ushort_t* vN2 = &Vt[2][0];

    for (int it = 0; it < 16; ++it) {
        int kt0 = it * 64;
        if (it < 15) { asm volatile("s_waitcnt vmcnt(4)" ::: "memory"); }
        else         { asm volatile("s_waitcnt vmcnt(0)" ::: "memory"); }
        BAR();
        __builtin_amdgcn_sched_barrier(0);
        if (it < 14) {
            int kn = kt0 + 128;
            char* kd = (char*)kN2 + wave * 1024;
            char* vd = (char*)vN2 + wave * 1024;
            glds16(kbase + (size_t)(kn + r0) * 64 + c0 * 8, kd);
            glds16(kbase + (size_t)(kn + r1) * 64 + c1 * 8, kd + 4096);
            glds16(vbase + (size_t)r0 * 1024 + kn + c0 * 8, vd);
            glds16(vbase + (size_t)r1 * 1024 + kn + c1 * 8, vd + 4096);
        }
        float mv[4];
        for (int nt = 0; nt < 4; ++nt) mv[nt] = mlds[kt0 + nt * 16 + l16];

#pragma unroll
        for (int ph = 0; ph < 2; ++ph) {
            f32x4 sacc[2][4];
            {
                short8 kf[4][2];
#pragma unroll
                for (int nt = 0; nt < 4; ++nt)
#pragma unroll
                    for (int kt = 0; kt < 2; ++kt)
                        kf[nt][kt] = *(const short8*)&kR[koff[nt][kt]];
#pragma unroll
                for (int mt = 0; mt < 2; ++mt)
#pragma unroll
                    for (int nt = 0; nt < 4; ++nt) {
                        f32x4 z = (f32x4)0.f;
                        z = MFMA16(qf[ph * 2 + mt][0], kf[nt][0], z);
                        z = MFMA16(qf[ph * 2 + mt][1], kf[nt][1], z);
                        sacc[mt][nt] = z;
                    }
            }
#pragma unroll
            for (int mt = 0; mt < 2; ++mt)
#pragma unroll
                for (int nt = 0; nt < 4; ++nt)
#pragma unroll
                    for (int r = 0; r < 4; ++r) {
                        float p = EXP2F(sacc[mt][nt][r] * KSCALE + mv[nt]);
                        Ps[wave][mt * 16 + quad * 4 + r][nt * 16 + l16] = f2bf(p);
                    }
            short8 pf[2][2];
#pragma unroll
            for (int mt = 0; mt < 2; ++mt)
#pragma unroll
                for (int kt = 0; kt < 2; ++kt)
                    pf[mt][kt] = *(const short8*)&Ps[wave][mt * 16 + l16][kt * 32 + quad * 8];
            {
                short8 vf[4][2];
#pragma unroll
                for (int nt = 0; nt < 4; ++nt)
#pragma unroll
                    for (int kt = 0; kt < 2; ++kt)
                        vf[nt][kt] = *(const short8*)&vR[voff[nt][kt]];
#pragma unroll
                for (int mt = 0; mt < 2; ++mt) {
#pragma unroll
                    for (int nt = 0; nt < 4; ++nt) {
                        oacc[ph * 2 + mt][nt] = MFMA16(pf[mt][0], vf[nt][0], oacc[ph * 2 + mt][nt]);
                        oacc[ph * 2 + mt][nt] = MFMA16(pf[mt][1], vf[nt][1], oacc[ph * 2 + mt][nt]);
                    }
                    sum_acc[ph * 2 + mt] = MFMA16(pf[mt][0], ones, sum_acc[ph * 2 + mt]);
                    sum_acc[ph * 2 + mt] = MFMA16(pf[mt][1], ones, sum_acc[ph * 2 + mt]);
                }
            }
        }
        const ushort_t* tk = kR; kR = kN1; kN1 = kN2; kN2 = tk;
        const ushort_t* tv = vR; vR = vN1; vN1 = vN2; vN2 = tv;
    }

    for (int mt = 0; mt < 4; ++mt) {
        for (int r = 0; r < 4; ++r) {
            float inv = 1.f / sum_acc[mt][r];
            int s = q0 + (mt >> 1) * 128 + (mt & 1) * 16 + quad * 4 + r;
            size_t ob = ((size_t)b * 1024 + s) * 1024 + h * 64;
            for (int nt = 0; nt < 4; ++nt)
                out[ob + nt * 16 + l16] = oacc[mt][nt][r] * inv;
        }
    }
}

extern "C" void kernel_launch(void* const* d_in, const int* in_sizes, int n_in,
                              void* d_out, int out_size, void* d_ws, size_t ws_size,
                              hipStream_t stream)
{
    const float* hidden = (const float*)d_in[0];
    const float* mask   = (const float*)d_in[1];
    const float* cosp   = (const float*)d_in[2];
    const float* sinp   = (const float*)d_in[3];
    const int* adapter_mask = (const int*)d_in[4];
    const float* W      = (const float*)d_in[5];
    const float* bias   = (const float*)d_in[6];
    const float* loraA  = (const float*)d_in[7];
    const float* loraB  = (const float*)d_in[8];
    float* out = (float*)d_out;

    char* ws = (char*)d_ws;
    float4* lo = (float4*)ws;                                  // 128 KB
    ushort_t* qw = (ushort_t*)(ws + (1 << 20));                // 16 MB each
    ushort_t* kw = qw + (size_t)8 * 16 * 1024 * 64;
    ushort_t* vt = kw + (size_t)8 * 16 * 1024 * 64;            // total 49 MB (proven fits)

    ushort_t* Hb = (ushort_t*)d_out;                           // 16 MB
    ushort_t* Wb = Hb + (size_t)8192 * 1024;                   // 6 MB

    prep_kernel<<<2816, 256, 0, stream>>>(hidden, W, loraA, adapter_mask, Hb, Wb, lo);
    qkv_gemm_kernel<<<1536, 256, 0, stream>>>(Hb, Wb, bias, lo, loraB, adapter_mask,
                                              cosp, sinp, qw, kw, vt);
    attn_kernel<<<512, 256, 0, stream>>>(qw, kw, vt, mask, out);
}